// Round 3
// baseline (733.273 us; speedup 1.0000x reference)
//
#include <hip/hip_runtime.h>

typedef unsigned short u16;
typedef __bf16   bf16x8 __attribute__((ext_vector_type(8)));
typedef float    f32x4  __attribute__((ext_vector_type(4)));
typedef unsigned short u16x8 __attribute__((ext_vector_type(8)));
typedef unsigned short u16x4 __attribute__((ext_vector_type(4)));

__device__ inline float bf2f(u16 u) { return __uint_as_float(((unsigned int)u) << 16); }
__device__ inline u16 f2bf(float f) {
    unsigned int u = __float_as_uint(f);
    u += 0x7FFF + ((u >> 16) & 1);   // round-to-nearest-even
    return (u16)(u >> 16);
}

// Load 8 consecutive elements as bf16(u16x8), from either an fp32 or bf16 array.
// elemIdx must be a multiple of 4 (16B fp32 alignment).
__device__ inline u16x8 load8any(const void* base, long elemIdx, int isF32) {
    if (isF32) {
        const float* p = (const float*)base + elemIdx;
        f32x4 v0 = *(const f32x4*)p;
        f32x4 v1 = *(const f32x4*)(p + 4);
        u16x8 r;
        r[0] = f2bf(v0[0]); r[1] = f2bf(v0[1]); r[2] = f2bf(v0[2]); r[3] = f2bf(v0[3]);
        r[4] = f2bf(v1[0]); r[5] = f2bf(v1[1]); r[6] = f2bf(v1[2]); r[7] = f2bf(v1[3]);
        return r;
    }
    return *(const u16x8*)((const u16*)base + elemIdx);
}

// Dtype sniff: even u16 indices of a bf16 gaussian array have exponent fields
// in [100,140]; of an fp32 array they are mantissa halves (uniform, ~16% in
// range). 64 samples, threshold 48 — decisive either way. flag: 0=bf16, 1=fp32.
__global__ void sniff_dtype(const u16* __restrict__ x, int* __restrict__ flag) {
    const int lane = threadIdx.x;                 // 64 threads
    const unsigned idx = lane * 131072u + 65536u; // even, max 8,323,072 < 8,388,608
    const u16 u = x[idx];
    const int e = (u >> 7) & 0xFF;
    const unsigned long long b = __ballot(e >= 100 && e <= 140);
    if (lane == 0) flag[0] = (__popcll(b) >= 48) ? 0 : 1;
}

__global__ void conv1d_any(const void* __restrict__ in, u16* __restrict__ out,
                           int n, const int* __restrict__ flagp) {
    const int i = blockIdx.x * 256 + threadIdx.x;
    if (i < n)
        out[i] = *flagp ? f2bf(((const float*)in)[i]) : ((const u16*)in)[i];
}

#define BK 32
#define LDSP 40   // 32 + 8 pad (16B-aligned rows; 2-way LDS conflicts are free per m136)

// C[M,N] = A[M,K] @ Bt[N,K]^T * scale (+ bias[N]).  M,N multiples of 128; K of 32.
// A_DYN: A may be fp32 (per *flagp). OUT_MODE: 0=bf16, 1=fp32, 2=dynamic per *flagp.
template <int A_DYN, int OUT_MODE, bool HAS_BIAS>
__global__ __launch_bounds__(256, 2)
void gemm128(const void* __restrict__ A, const u16* __restrict__ Bt,
             void* __restrict__ Cv, const u16* __restrict__ bias,
             int K, long lda, long ldb, long ldc, long aOff, long cOff,
             float scale, const int* __restrict__ flagp)
{
    __shared__ __align__(16) u16 As[128][LDSP];
    __shared__ __align__(16) u16 Bs[128][LDSP];

    const int aF32   = A_DYN ? *flagp : 0;
    const int outF32 = (OUT_MODE == 2) ? *flagp : 0;

    const int tid  = threadIdx.x;
    const int lane = tid & 63;
    const int wave = tid >> 6;
    const long m0 = (long)blockIdx.y * 128;
    const long n0 = (long)blockIdx.x * 128;

    // staging: thread t covers tile row t/2, k-half (t&1)*16 (16 elements)
    const int srow = tid >> 1;
    const int scol = (tid & 1) * 16;
    long aIdx = aOff + (m0 + srow) * lda + scol;
    long bIdx = (n0 + srow) * ldb + scol;

    const int wm = (wave >> 1) * 64;   // wave tile origin in M
    const int wn = (wave & 1) * 64;    // wave tile origin in N
    const int lr = lane & 15;          // m (A) / n (B) within 16
    const int lk = (lane >> 4) * 8;    // k-offset of the 8-elem fragment

    f32x4 acc[4][4] = {};

    for (int kt = 0; kt < K; kt += BK) {
        u16x8 a0 = load8any(A, aIdx,     aF32);
        u16x8 a1 = load8any(A, aIdx + 8, aF32);
        u16x8 b0 = *(const u16x8*)(Bt + bIdx);
        u16x8 b1 = *(const u16x8*)(Bt + bIdx + 8);
        aIdx += BK; bIdx += BK;
        __syncthreads();   // previous iter's LDS reads done
        *(u16x8*)&As[srow][scol]     = a0;
        *(u16x8*)&As[srow][scol + 8] = a1;
        *(u16x8*)&Bs[srow][scol]     = b0;
        *(u16x8*)&Bs[srow][scol + 8] = b1;
        __syncthreads();

        bf16x8 af[4], bf[4];
#pragma unroll
        for (int i = 0; i < 4; ++i) af[i] = *(const bf16x8*)&As[wm + i*16 + lr][lk];
#pragma unroll
        for (int j = 0; j < 4; ++j) bf[j] = *(const bf16x8*)&Bs[wn + j*16 + lr][lk];
#pragma unroll
        for (int i = 0; i < 4; ++i)
#pragma unroll
            for (int j = 0; j < 4; ++j)
                acc[i][j] = __builtin_amdgcn_mfma_f32_16x16x32_bf16(af[i], bf[j], acc[i][j], 0, 0, 0);
    }

    // epilogue: C/D layout col = lane&15, row = (lane>>4)*4 + r   [m89/m91 verified]
#pragma unroll
    for (int j = 0; j < 4; ++j) {
        const long c = n0 + wn + j*16 + lr;
        const float bj = HAS_BIAS ? bf2f(bias[c]) : 0.0f;
#pragma unroll
        for (int i = 0; i < 4; ++i) {
            const long rbase = m0 + wm + i*16 + (lane >> 4) * 4;
#pragma unroll
            for (int r = 0; r < 4; ++r) {
                const float v = acc[i][j][r] * scale + bj;
                const long ci = cOff + (rbase + r) * ldc + c;
                if (OUT_MODE == 1)        ((float*)Cv)[ci] = v;
                else if (OUT_MODE == 0)   ((u16*)Cv)[ci]   = f2bf(v);
                else { if (outF32) ((float*)Cv)[ci] = v; else ((u16*)Cv)[ci] = f2bf(v); }
            }
        }
    }
}

// out[c][r] = in[r][c], 32x32 LDS tiles; input either fp32 or bf16 per *flagp.
__global__ __launch_bounds__(256)
void transpose_any(const void* __restrict__ in, u16* __restrict__ out,
                   long inStride, long outStride, const int* __restrict__ flagp)
{
    __shared__ u16 t[32][36];
    const int isF32 = *flagp;
    const int tid = threadIdx.x;
    const long r0 = (long)blockIdx.y * 32;
    const long c0 = (long)blockIdx.x * 32;
    const int r  = tid >> 3;        // 0..31
    const int c4 = (tid & 7) * 4;   // 0..28
    const long base = (r0 + r) * inStride + c0 + c4;
    u16x4 v;
    if (isF32) {
        f32x4 f = *(const f32x4*)((const float*)in + base);
        v[0] = f2bf(f[0]); v[1] = f2bf(f[1]); v[2] = f2bf(f[2]); v[3] = f2bf(f[3]);
    } else {
        v = *(const u16x4*)((const u16*)in + base);
    }
    t[r][c4 + 0] = v[0]; t[r][c4 + 1] = v[1]; t[r][c4 + 2] = v[2]; t[r][c4 + 3] = v[3];
    __syncthreads();
    u16x4 o;
    o[0] = t[c4 + 0][r]; o[1] = t[c4 + 1][r]; o[2] = t[c4 + 2][r]; o[3] = t[c4 + 3][r];
    *(u16x4*)&out[(c0 + r) * outStride + r0 + c4] = o;
}

// bf16-only transpose (for V^T from canonical QKV).
__global__ __launch_bounds__(256)
void transpose_bf16(const u16* __restrict__ in, u16* __restrict__ out,
                    long inStride, long outStride)
{
    __shared__ u16 t[32][36];
    const int tid = threadIdx.x;
    const long r0 = (long)blockIdx.y * 32;
    const long c0 = (long)blockIdx.x * 32;
    const int r  = tid >> 3;
    const int c4 = (tid & 7) * 4;
    u16x4 v = *(const u16x4*)&in[(r0 + r) * inStride + c0 + c4];
    t[r][c4 + 0] = v[0]; t[r][c4 + 1] = v[1]; t[r][c4 + 2] = v[2]; t[r][c4 + 3] = v[3];
    __syncthreads();
    u16x4 o;
    o[0] = t[c4 + 0][r]; o[1] = t[c4 + 1][r]; o[2] = t[c4 + 2][r]; o[3] = t[c4 + 3][r];
    *(u16x4*)&out[(c0 + r) * outStride + r0 + c4] = o;
}

// One block per row of 2048 fp32 scores; writes bf16 probs in-place into the
// low half (u16 cols 0..2047) of the row; all reads precede the first barrier.
__global__ __launch_bounds__(256)
void softmax_inplace(float* __restrict__ scores)
{
    float* p = scores + (size_t)blockIdx.x * 2048;
    const int tid = threadIdx.x;
    const int wave = tid >> 6, lane = tid & 63;
    float x[8];
#pragma unroll
    for (int i = 0; i < 8; ++i) x[i] = p[tid + i * 256];
    float m = x[0];
#pragma unroll
    for (int i = 1; i < 8; ++i) m = fmaxf(m, x[i]);
#pragma unroll
    for (int o = 32; o; o >>= 1) m = fmaxf(m, __shfl_xor(m, o));
    __shared__ float red[4];
    if (lane == 0) red[wave] = m;
    __syncthreads();
    m = fmaxf(fmaxf(red[0], red[1]), fmaxf(red[2], red[3]));
    float e[8], s = 0.0f;
#pragma unroll
    for (int i = 0; i < 8; ++i) { e[i] = __expf(x[i] - m); s += e[i]; }
#pragma unroll
    for (int o = 32; o; o >>= 1) s += __shfl_xor(s, o);
    __syncthreads();
    if (lane == 0) red[wave] = s;
    __syncthreads();
    s = red[0] + red[1] + red[2] + red[3];
    const float inv = 1.0f / s;
    u16* ob = (u16*)p;
#pragma unroll
    for (int i = 0; i < 8; ++i) ob[tid + i * 256] = f2bf(e[i] * inv);
}

extern "C" void kernel_launch(void* const* d_in, const int* in_sizes, int n_in,
                              void* d_out, int out_size, void* d_ws, size_t ws_size,
                              hipStream_t stream)
{
    const void* x    = d_in[0];   // [4][2048][1024]  fp32 or bf16
    const void* Wqkv = d_in[1];   // [1024][3072]
    const void* bqkv = d_in[2];   // [3072]
    const void* Wout = d_in[3];   // [1024][1024]
    const void* bout = d_in[4];   // [1024]
    char* ws = (char*)d_ws;

    // workspace layout — 41 MB total
    u16*   WqkvT = (u16*)(ws);                 //  6 MB  [3072][1024] bf16
    u16*   WoutT = (u16*)(ws + 6291456);       //  2 MB  [1024][1024] bf16
    u16*   bqkvc = (u16*)(ws + 8388608);       //  6 KB  bf16
    u16*   boutc = (u16*)(ws + 8394752);       //  2 KB  bf16
    int*   flag  = (int*)(ws + 8396800);       //  4 B   0=bf16, 1=fp32
    u16*   QKVb  = (u16*)(ws + 9437184);       // 12 MB  [2048][3072] bf16 (per-batch)
    u16*   VTb   = (u16*)(ws + 22020096);      //  4 MB  [1024][2048] bf16 (per-batch)
    float* SCb   = (float*)(ws + 26214400);    // 16 MB  [2048][2048] fp32 (per-batch)
    u16*   SCu   = (u16*)SCb;                  // after softmax: probs u16 cols 0..2047,
                                               // context embedded in u16 cols 2048..3071

    dim3 blk(256);

    sniff_dtype<<<1, 64, 0, stream>>>((const u16*)x, flag);
    conv1d_any<<<12, blk, 0, stream>>>(bqkv, bqkvc, 3072, flag);
    conv1d_any<<<4, blk, 0, stream>>>(bout, boutc, 1024, flag);
    transpose_any<<<dim3(96, 32), blk, 0, stream>>>(Wqkv, WqkvT, 3072L, 1024L, flag);
    transpose_any<<<dim3(32, 32), blk, 0, stream>>>(Wout, WoutT, 1024L, 1024L, flag);

    for (int b = 0; b < 4; ++b) {
        const long xOff   = (long)b * 2048 * 1024;
        const long outOff = (long)b * 2048 * 1024;

        // QKV_b = x_b @ Wqkv + b_qkv      [2048,1024]@[1024,3072] -> bf16
        gemm128<1, 0, true><<<dim3(24, 16), blk, 0, stream>>>(
            x, WqkvT, QKVb, bqkvc, 1024, 1024L, 1024L, 3072L, xOff, 0L, 1.0f, flag);

        // V^T[e][s] = QKV_b[s][2048+e]
        transpose_bf16<<<dim3(32, 64), blk, 0, stream>>>(QKVb + 2048, VTb, 3072L, 2048L);

        // scores = Q @ K^T * 0.125  -> fp32 [2048,2048]
        gemm128<0, 1, false><<<dim3(16, 16), blk, 0, stream>>>(
            QKVb, QKVb + 1024, SCb, nullptr, 1024, 3072L, 3072L, 2048L, 0L, 0L, 0.125f, nullptr);

        // softmax rows -> bf16 probs in-place (low half of each fp32 row)
        softmax_inplace<<<dim3(2048), blk, 0, stream>>>(SCb);

        // context = attn @ V -> dead upper half of score rows (cols disjoint from reads)
        gemm128<0, 0, false><<<dim3(8, 16), blk, 0, stream>>>(
            SCu, VTb, SCu + 2048, nullptr, 2048, 4096L, 2048L, 4096L, 0L, 0L, 1.0f, nullptr);

        // out_b = context @ Wout + b_out   [2048,1024]@[1024,1024] -> output dtype
        gemm128<0, 2, true><<<dim3(8, 16), blk, 0, stream>>>(
            SCu + 2048, WoutT, d_out, boutc, 1024, 4096L, 1024L, 1024L, 0L, outOff, 1.0f, flag);
    }
}

// Round 4
// 340.609 us; speedup vs baseline: 2.1528x; 2.1528x over previous
//
#include <hip/hip_runtime.h>

typedef unsigned short u16;
typedef __bf16   bf16x8 __attribute__((ext_vector_type(8)));
typedef float    f32x4  __attribute__((ext_vector_type(4)));
typedef unsigned short u16x4 __attribute__((ext_vector_type(4)));

__device__ inline float bf2f(u16 u) { return __uint_as_float(((unsigned int)u) << 16); }
__device__ inline u16 f2bf(float f) {
    unsigned int u = __float_as_uint(f);
    u += 0x7FFF + ((u >> 16) & 1);   // round-to-nearest-even
    return (u16)(u >> 16);
}

// async global->LDS, 16B per lane. LDS dest must be wave-uniform base; HW adds lane*16.
__device__ inline void gl2lds16(const u16* g, u16* l) {
    __builtin_amdgcn_global_load_lds(
        (const __attribute__((address_space(1))) void*)g,
        (__attribute__((address_space(3))) void*)l, 16, 0, 0);
}

// Dtype sniff: even u16 indices of a bf16 gaussian array have exponent fields in
// [100,140]; of an fp32 array they are mantissa halves (uniform). flag: 0=bf16, 1=fp32.
__global__ void sniff_dtype(const u16* __restrict__ x, int* __restrict__ flag) {
    const int lane = threadIdx.x;                 // 64 threads
    const unsigned idx = lane * 131072u + 65536u;
    const u16 u = x[idx];
    const int e = (u >> 7) & 0xFF;
    const unsigned long long b = __ballot(e >= 100 && e <= 140);
    if (lane == 0) flag[0] = (__popcll(b) >= 48) ? 0 : 1;
}

// x (fp32 or bf16 per flag) -> bf16, 4 elems/thread
__global__ __launch_bounds__(256)
void convx(const void* __restrict__ in, u16* __restrict__ out, const int* __restrict__ flagp) {
    const long i = ((long)blockIdx.x * 256 + threadIdx.x) * 4;
    if (*flagp) {
        f32x4 v = *(const f32x4*)((const float*)in + i);
        u16x4 o; o[0] = f2bf(v[0]); o[1] = f2bf(v[1]); o[2] = f2bf(v[2]); o[3] = f2bf(v[3]);
        *(u16x4*)(out + i) = o;
    } else {
        *(u16x4*)(out + i) = *(const u16x4*)((const u16*)in + i);
    }
}

__global__ void conv1d_any(const void* __restrict__ in, u16* __restrict__ out,
                           int n, const int* __restrict__ flagp) {
    const int i = blockIdx.x * 256 + threadIdx.x;
    if (i < n)
        out[i] = *flagp ? f2bf(((const float*)in)[i]) : ((const u16*)in)[i];
}

// C[M,N] = A[M,K] @ Bt[N,K]^T * scale (+ bias[N]); bf16 in, unpadded LDS,
// global_load_lds(16B) staging, m97 2-barrier K-loop.
// OUT_MODE: 0=bf16, 1=fp32, 2=dynamic per *flagp (1 -> fp32).
template <int OUT_MODE, bool HAS_BIAS>
__global__ __launch_bounds__(256, 2)
void gemm128(const u16* __restrict__ A, const u16* __restrict__ Bt,
             void* __restrict__ Cv, const u16* __restrict__ bias,
             int K, long lda, long ldb, long ldc,
             long aBatch, long bBatch, long cBatch, float scale,
             const int* __restrict__ flagp)
{
    __shared__ __align__(16) u16 As[128 * 32];   // 8 KB, unpadded (global_load_lds layout)
    __shared__ __align__(16) u16 Bs[128 * 32];

    const int outF32 = (OUT_MODE == 2) ? *flagp : OUT_MODE;

    const int tid  = threadIdx.x;
    const int lane = tid & 63;
    const int wave = tid >> 6;
    const long m0 = (long)blockIdx.y * 128;
    const long n0 = (long)blockIdx.x * 128;
    const long bz = blockIdx.z;

    // staging: 16B chunk c covers LDS row c>>2, u16 col (c&3)*8.
    // chunk c = issue*256 + wave*64 + lane  ->  LDS dest uniform per (issue,wave).
    const int c0 = tid, c1 = 256 + tid;
    const u16* pa0 = A  + bz * aBatch + (m0 + (c0 >> 2)) * lda + (c0 & 3) * 8;
    const u16* pa1 = A  + bz * aBatch + (m0 + (c1 >> 2)) * lda + (c1 & 3) * 8;
    const u16* pb0 = Bt + bz * bBatch + (n0 + (c0 >> 2)) * ldb + (c0 & 3) * 8;
    const u16* pb1 = Bt + bz * bBatch + (n0 + (c1 >> 2)) * ldb + (c1 & 3) * 8;
    u16* lA0 = As + (wave * 64) * 8;
    u16* lA1 = As + (256 + wave * 64) * 8;
    u16* lB0 = Bs + (wave * 64) * 8;
    u16* lB1 = Bs + (256 + wave * 64) * 8;

    const int wm = (wave >> 1) * 64;   // wave tile origin in M
    const int wn = (wave & 1) * 64;    // wave tile origin in N
    const int lr = lane & 15;          // m (A) / n (B) within 16
    const int lk = (lane >> 4) * 8;    // k-offset of the 8-elem fragment

    f32x4 acc[4][4] = {};

    for (int kt = 0; kt < K; kt += 32) {
        gl2lds16(pa0, lA0);
        gl2lds16(pa1, lA1);
        gl2lds16(pb0, lB0);
        gl2lds16(pb1, lB1);
        pa0 += 32; pa1 += 32; pb0 += 32; pb1 += 32;
        __syncthreads();   // drains vmcnt (LDS writes landed) + barrier

        bf16x8 af[4], bf[4];
#pragma unroll
        for (int i = 0; i < 4; ++i) af[i] = *(const bf16x8*)&As[(wm + i*16 + lr) * 32 + lk];
#pragma unroll
        for (int j = 0; j < 4; ++j) bf[j] = *(const bf16x8*)&Bs[(wn + j*16 + lr) * 32 + lk];
#pragma unroll
        for (int i = 0; i < 4; ++i)
#pragma unroll
            for (int j = 0; j < 4; ++j)
                acc[i][j] = __builtin_amdgcn_mfma_f32_16x16x32_bf16(af[i], bf[j], acc[i][j], 0, 0, 0);
        __syncthreads();   // all waves done reading before next overwrite
    }

    // epilogue: C/D layout col = lane&15, row = (lane>>4)*4 + r   [m89/m91 verified]
#pragma unroll
    for (int j = 0; j < 4; ++j) {
        const long c = n0 + wn + j*16 + lr;
        const float bj = HAS_BIAS ? bf2f(bias[c]) : 0.0f;
#pragma unroll
        for (int i = 0; i < 4; ++i) {
            const long rbase = m0 + wm + i*16 + (lane >> 4) * 4;
#pragma unroll
            for (int r = 0; r < 4; ++r) {
                const float v = acc[i][j][r] * scale + bj;
                const long ci = bz * cBatch + (rbase + r) * ldc + c;
                if (outF32) ((float*)Cv)[ci] = v;
                else        ((u16*)Cv)[ci]   = f2bf(v);
            }
        }
    }
}

// out[c][r] = in[r][c], 32x32 LDS tiles; input fp32 or bf16 per *flagp.
__global__ __launch_bounds__(256)
void transpose_any(const void* __restrict__ in, u16* __restrict__ out,
                   long inStride, long outStride, const int* __restrict__ flagp)
{
    __shared__ u16 t[32][36];
    const int isF32 = *flagp;
    const int tid = threadIdx.x;
    const long r0 = (long)blockIdx.y * 32;
    const long c0 = (long)blockIdx.x * 32;
    const int r  = tid >> 3;
    const int c4 = (tid & 7) * 4;
    const long base = (r0 + r) * inStride + c0 + c4;
    u16x4 v;
    if (isF32) {
        f32x4 f = *(const f32x4*)((const float*)in + base);
        v[0] = f2bf(f[0]); v[1] = f2bf(f[1]); v[2] = f2bf(f[2]); v[3] = f2bf(f[3]);
    } else {
        v = *(const u16x4*)((const u16*)in + base);
    }
    t[r][c4 + 0] = v[0]; t[r][c4 + 1] = v[1]; t[r][c4 + 2] = v[2]; t[r][c4 + 3] = v[3];
    __syncthreads();
    u16x4 o;
    o[0] = t[c4 + 0][r]; o[1] = t[c4 + 1][r]; o[2] = t[c4 + 2][r]; o[3] = t[c4 + 3][r];
    *(u16x4*)&out[(c0 + r) * outStride + r0 + c4] = o;
}

// bf16 transpose with batch strides (for V^T), z = batch.
__global__ __launch_bounds__(256)
void transpose_bf16(const u16* __restrict__ in, u16* __restrict__ out,
                    long inStride, long outStride, long inBatch, long outBatch)
{
    __shared__ u16 t[32][36];
    const int tid = threadIdx.x;
    const long r0 = (long)blockIdx.y * 32;
    const long c0 = (long)blockIdx.x * 32;
    in  += (long)blockIdx.z * inBatch;
    out += (long)blockIdx.z * outBatch;
    const int r  = tid >> 3;
    const int c4 = (tid & 7) * 4;
    u16x4 v = *(const u16x4*)&in[(r0 + r) * inStride + c0 + c4];
    t[r][c4 + 0] = v[0]; t[r][c4 + 1] = v[1]; t[r][c4 + 2] = v[2]; t[r][c4 + 3] = v[3];
    __syncthreads();
    u16x4 o;
    o[0] = t[c4 + 0][r]; o[1] = t[c4 + 1][r]; o[2] = t[c4 + 2][r]; o[3] = t[c4 + 3][r];
    *(u16x4*)&out[(c0 + r) * outStride + r0 + c4] = o;
}

// One block per row of 2048 fp32 scores; bf16 probs in-place into the low half
// of the row (all reads precede the first barrier, which precedes all writes).
__global__ __launch_bounds__(256)
void softmax_inplace(float* __restrict__ scores)
{
    float* p = scores + (size_t)blockIdx.x * 2048;
    const int tid = threadIdx.x;
    const int wave = tid >> 6, lane = tid & 63;
    float x[8];
#pragma unroll
    for (int i = 0; i < 8; ++i) x[i] = p[tid + i * 256];
    float m = x[0];
#pragma unroll
    for (int i = 1; i < 8; ++i) m = fmaxf(m, x[i]);
#pragma unroll
    for (int o = 32; o; o >>= 1) m = fmaxf(m, __shfl_xor(m, o));
    __shared__ float red[4];
    if (lane == 0) red[wave] = m;
    __syncthreads();
    m = fmaxf(fmaxf(red[0], red[1]), fmaxf(red[2], red[3]));
    float e[8], s = 0.0f;
#pragma unroll
    for (int i = 0; i < 8; ++i) { e[i] = __expf(x[i] - m); s += e[i]; }
#pragma unroll
    for (int o = 32; o; o >>= 1) s += __shfl_xor(s, o);
    __syncthreads();
    if (lane == 0) red[wave] = s;
    __syncthreads();
    s = red[0] + red[1] + red[2] + red[3];
    const float inv = 1.0f / s;
    u16* ob = (u16*)p;
#pragma unroll
    for (int i = 0; i < 8; ++i) ob[tid + i * 256] = f2bf(e[i] * inv);
}

extern "C" void kernel_launch(void* const* d_in, const int* in_sizes, int n_in,
                              void* d_out, int out_size, void* d_ws, size_t ws_size,
                              hipStream_t stream)
{
    const void* x    = d_in[0];   // [4][2048][1024] fp32 (or bf16; sniffed)
    const void* Wqkv = d_in[1];   // [1024][3072]
    const void* bqkv = d_in[2];   // [3072]
    const void* Wout = d_in[3];   // [1024][1024]
    const void* bout = d_in[4];   // [1024]
    char* ws = (char*)d_ws;

    // workspace — 136.4 MB, alias-packed:
    //   SC region [0, 64MB): fp32 scores [4][2048][2048]. Before scores are
    //   written it hosts xbf @0 (16MB) and WqkvT @16MB (6MB) — both fully
    //   consumed by the QKV GEMM, which completes before the scores GEMM.
    float* SC    = (float*)(ws);
    u16*   SCu   = (u16*)(ws);                  // post-softmax probs (u16 cols 0..2047)
                                                // + context in u16 cols 2048..3071
    u16*   xbf   = (u16*)(ws);                  // 16 MB  [8192][1024] bf16 (aliases SC)
    u16*   WqkvT = (u16*)(ws + 16777216);       //  6 MB  [3072][1024] bf16 (aliases SC)
    u16*   QKV   = (u16*)(ws + 67108864);       // 48 MB  [8192][3072] bf16
    u16*   VT    = (u16*)(ws + 117440512);      // 16 MB  [4][1024][2048] bf16
    u16*   WoutT = (u16*)(ws + 134217728);      //  2 MB  [1024][1024] bf16
    u16*   bqkvc = (u16*)(ws + 136314880);      //  6 KB
    u16*   boutc = (u16*)(ws + 136321024);      //  2 KB
    int*   flag  = (int*)(ws + 136323072);      //  4 B   0=bf16, 1=fp32

    dim3 blk(256);

    sniff_dtype<<<1, 64, 0, stream>>>((const u16*)x, flag);
    convx<<<8192, blk, 0, stream>>>(x, xbf, flag);
    conv1d_any<<<12, blk, 0, stream>>>(bqkv, bqkvc, 3072, flag);
    conv1d_any<<<4, blk, 0, stream>>>(bout, boutc, 1024, flag);
    transpose_any<<<dim3(96, 32), blk, 0, stream>>>(Wqkv, WqkvT, 3072L, 1024L, flag);
    transpose_any<<<dim3(32, 32), blk, 0, stream>>>(Wout, WoutT, 1024L, 1024L, flag);

    // QKV = xbf @ Wqkv + b_qkv    [8192,1024]@[1024,3072], single M=8192 GEMM
    gemm128<0, true><<<dim3(24, 64, 1), blk, 0, stream>>>(
        xbf, WqkvT, QKV, bqkvc, 1024, 1024L, 1024L, 3072L, 0L, 0L, 0L, 1.0f, nullptr);

    // V^T[b][e][s] = QKV[b][s][2048+e]
    transpose_bf16<<<dim3(32, 64, 4), blk, 0, stream>>>(
        QKV + 2048, VT, 3072L, 2048L, 2048L * 3072L, 1024L * 2048L);

    // scores = Q @ K^T * 0.125 -> fp32, z = batch
    gemm128<1, false><<<dim3(16, 16, 4), blk, 0, stream>>>(
        QKV, QKV + 1024, SC, nullptr, 1024, 3072L, 3072L, 2048L,
        2048L * 3072L, 2048L * 3072L, 2048L * 2048L, 0.125f, nullptr);

    // softmax all 8192 rows -> bf16 probs in-place
    softmax_inplace<<<dim3(8192), blk, 0, stream>>>(SC);

    // context = attn @ V -> embedded in dead upper half of score rows, z = batch
    gemm128<0, false><<<dim3(8, 16, 4), blk, 0, stream>>>(
        SCu, VT, SCu + 2048, nullptr, 2048, 4096L, 2048L, 4096L,
        2048L * 4096L, 1024L * 2048L, 2048L * 4096L, 1.0f, nullptr);

    // out = context @ Wout + b_out, single M=8192 GEMM (batch rows contiguous at lda=4096)
    gemm128<2, true><<<dim3(8, 64, 1), blk, 0, stream>>>(
        SCu + 2048, WoutT, d_out, boutc, 1024, 4096L, 1024L, 1024L,
        0L, 0L, 0L, 1.0f, flag);
}